// Round 5
// baseline (442.409 us; speedup 1.0000x reference)
//
#include <hip/hip_runtime.h>
#include <math.h>

#define HN 16
#define SEQ 1024
#define DMODEL 1024
#define DH 64
#define SM1 1023   // S-1

typedef float  f32x4  __attribute__((ext_vector_type(4)));
typedef __bf16 bf16x8 __attribute__((ext_vector_type(8)));

// ---------------------------------------------------------------
// MFMA GEMM with bf16 hi/lo split (3 MFMAs ~ fp32 precision).
// out = X[M x 1024] @ W[1024 x 1024] + bias
// MODE 0: head-split bf16 hi/lo planes out[bh][s(SEQ)][64]
// MODE 1: plain fp32 out[m][1024]
// MODE 2: transposed bf16 hi/lo planes out[bh][dh][1024(pad)]
// Tile 64x64, BK=32, 256 threads / 4 waves (wave = 16 rows x 64 cols).
// LDS layout: row*128B, 8 slots of 16B; element (row,k,plane):
//   slot = (2*(k>>3) + plane) ^ (row&7)  -> 2-way max in every
//   quarter-wave for BOTH staging writes and fragment reads.
// ---------------------------------------------------------------
template<int MODE>
__global__ __launch_bounds__(256)
void gemm_mfma_kernel(const float* __restrict__ X, const float* __restrict__ W,
                      const float* __restrict__ bias, float* __restrict__ out32,
                      __bf16* __restrict__ outHi, __bf16* __restrict__ outLo,
                      int M, int rows)
{
    __shared__ __align__(16) __bf16 As[4096];  // 8KB
    __shared__ __align__(16) __bf16 Bs[4096];  // 8KB

    const int t  = threadIdx.x;
    const int w  = t >> 6, l = t & 63;
    const int lr = l & 15, ls = l >> 4;
    const int m0 = blockIdx.y * 64, n0 = blockIdx.x * 64;
    const int sr  = t >> 2;       // staging row (A) / col (B), 0..63
    const int skq = t & 3;        // staging k-chunk (8 elems)

    f32x4 acc[4];
#pragma unroll
    for (int ct = 0; ct < 4; ++ct) acc[ct] = f32x4{0.f, 0.f, 0.f, 0.f};

    // fragment LDS byte addrs (A): row = w*16+lr, chunk = ls
    const int ar   = w * 16 + lr;
    const int a_hi = ar * 128 + (((2 * ls    ) ^ (ar & 7)) << 4);
    const int a_lo = ar * 128 + (((2 * ls + 1) ^ (ar & 7)) << 4);
    // staging byte addrs
    const int st_hi = sr * 128 + (((2 * skq    ) ^ (sr & 7)) << 4);
    const int st_lo = sr * 128 + (((2 * skq + 1) ^ (sr & 7)) << 4);

    for (int k0 = 0; k0 < DMODEL; k0 += 32) {
        __syncthreads();
        // ---- stage A (64 rows x 32 k) ----
        {
            float xv[8];
            if (m0 + sr < M) {
                float4 v0 = *(const float4*)&X[(size_t)(m0 + sr) * DMODEL + k0 + skq * 8];
                float4 v1 = *(const float4*)&X[(size_t)(m0 + sr) * DMODEL + k0 + skq * 8 + 4];
                xv[0] = v0.x; xv[1] = v0.y; xv[2] = v0.z; xv[3] = v0.w;
                xv[4] = v1.x; xv[5] = v1.y; xv[6] = v1.z; xv[7] = v1.w;
            } else {
#pragma unroll
                for (int e = 0; e < 8; ++e) xv[e] = 0.f;
            }
            bf16x8 h8, l8;
#pragma unroll
            for (int e = 0; e < 8; ++e) {
                __bf16 hb = (__bf16)xv[e];
                h8[e] = hb;
                l8[e] = (__bf16)(xv[e] - (float)hb);
            }
            *(bf16x8*)((char*)As + st_hi) = h8;
            *(bf16x8*)((char*)As + st_lo) = l8;
        }
        // ---- stage B (32 k x 64 cols, stored [col][k]) ----
        {
            float wv[8];
#pragma unroll
            for (int e = 0; e < 8; ++e)
                wv[e] = W[(size_t)(k0 + skq * 8 + e) * DMODEL + n0 + sr];
            bf16x8 h8, l8;
#pragma unroll
            for (int e = 0; e < 8; ++e) {
                __bf16 hb = (__bf16)wv[e];
                h8[e] = hb;
                l8[e] = (__bf16)(wv[e] - (float)hb);
            }
            *(bf16x8*)((char*)Bs + st_hi) = h8;
            *(bf16x8*)((char*)Bs + st_lo) = l8;
        }
        __syncthreads();

        const bf16x8 ah = *(const bf16x8*)((const char*)As + a_hi);
        const bf16x8 al = *(const bf16x8*)((const char*)As + a_lo);
#pragma unroll
        for (int ct = 0; ct < 4; ++ct) {
            const int bc   = ct * 16 + lr;
            const int b_hi = bc * 128 + (((2 * ls    ) ^ (bc & 7)) << 4);
            const int b_lo = bc * 128 + (((2 * ls + 1) ^ (bc & 7)) << 4);
            const bf16x8 bh = *(const bf16x8*)((const char*)Bs + b_hi);
            const bf16x8 bl = *(const bf16x8*)((const char*)Bs + b_lo);
            acc[ct] = __builtin_amdgcn_mfma_f32_16x16x32_bf16(ah, bh, acc[ct], 0, 0, 0);
            acc[ct] = __builtin_amdgcn_mfma_f32_16x16x32_bf16(al, bh, acc[ct], 0, 0, 0);
            acc[ct] = __builtin_amdgcn_mfma_f32_16x16x32_bf16(ah, bl, acc[ct], 0, 0, 0);
        }
    }

    // ---- epilogue ----
#pragma unroll
    for (int ct = 0; ct < 4; ++ct) {
        const int n = n0 + ct * 16 + lr;
        const float bv = bias[n];
#pragma unroll
        for (int j = 0; j < 4; ++j) {
            const int m = m0 + w * 16 + ls * 4 + j;
            if (m >= M) continue;
            const float val = acc[ct][j] + bv;
            if (MODE == 1) {
                out32[(size_t)m * DMODEL + n] = val;
            } else {
                const int bb = m / rows, s = m - bb * rows;
                const __bf16 hb = (__bf16)val;
                const __bf16 lb = (__bf16)(val - (float)hb);
                size_t idx;
                if (MODE == 0)
                    idx = (((size_t)(bb * HN + (n >> 6)) * SEQ + s) << 6) + (n & 63);
                else // MODE 2
                    idx = (((size_t)(bb * HN + (n >> 6)) * DH + (n & 63)) << 10) + s;
                outHi[idx] = hb; outLo[idx] = lb;
            }
        }
    }
}

// ---------------------------------------------------------------
// Fused attention: two-pass flash-style.
// Block = 64 q-rows x all 1023 keys x one (b,h). 4 waves, each owning
// 16 rows. Pass 1: QK (hi/lo MFMA) + relu/mask -> sum of exp (no max
// subtraction; relu-capped logits can't overflow exp). Pass 2:
// recompute QK, normalize, stage P tile in LDS, write weights
// coalesced, PV via MFMA (P hi/lo x V hi/lo planes).
// ---------------------------------------------------------------
__global__ __launch_bounds__(256, 2)
void fused_attn_kernel(const __bf16* __restrict__ qhi, const __bf16* __restrict__ qlo,
                       const __bf16* __restrict__ khi, const __bf16* __restrict__ klo,
                       const __bf16* __restrict__ vthi, const __bf16* __restrict__ vtlo,
                       const int* __restrict__ mask, float* __restrict__ att,
                       float* __restrict__ ctx)
{
    __shared__ __align__(16) float P[64 * 68];   // normalized weight tile

    const int b = blockIdx.z, h = blockIdx.y, bh = b * HN + h;
    const int t = threadIdx.x;
    const int w = t >> 6, l = t & 63;
    const int lr = l & 15, ls = l >> 4;
    const int row0 = blockIdx.x * 64 + w * 16;   // wave's 16 rows

    // ---- Q fragments (row lr of wave tile; q row = att row + 1) ----
    const int r_a  = row0 + lr;
    const int qrow = (r_a < SM1 ? r_a : SM1 - 1) + 1;
    const size_t qb = ((size_t)bh * SEQ + qrow) * DH + ls * 8;
    const bf16x8 a0h = *(const bf16x8*)&qhi[qb];
    const bf16x8 a0l = *(const bf16x8*)&qlo[qb];
    const bf16x8 a1h = *(const bf16x8*)&qhi[qb + 32];
    const bf16x8 a1l = *(const bf16x8*)&qlo[qb + 32];

    const int rr0 = row0 + ls * 4;               // C rows rr0..rr0+3

    // ================= pass 1: sum of exp =================
    float s[4] = {0.f, 0.f, 0.f, 0.f};
    for (int kt = 0; kt < 16; ++kt) {
        const int kb0 = kt * 64;
#pragma unroll
        for (int ct = 0; ct < 4; ++ct) {
            const int c    = kb0 + ct * 16 + lr;
            const int krow = (c < SM1) ? c : SM1 - 1;
            const size_t kbq = ((size_t)bh * SEQ + krow) * DH + ls * 8;
            const bf16x8 b0h = *(const bf16x8*)&khi[kbq];
            const bf16x8 b0l = *(const bf16x8*)&klo[kbq];
            const bf16x8 b1h = *(const bf16x8*)&khi[kbq + 32];
            const bf16x8 b1l = *(const bf16x8*)&klo[kbq + 32];

            f32x4 acc = {0.f, 0.f, 0.f, 0.f};
            acc = __builtin_amdgcn_mfma_f32_16x16x32_bf16(a0h, b0h, acc, 0, 0, 0);
            acc = __builtin_amdgcn_mfma_f32_16x16x32_bf16(a0l, b0h, acc, 0, 0, 0);
            acc = __builtin_amdgcn_mfma_f32_16x16x32_bf16(a0h, b0l, acc, 0, 0, 0);
            acc = __builtin_amdgcn_mfma_f32_16x16x32_bf16(a1h, b1h, acc, 0, 0, 0);
            acc = __builtin_amdgcn_mfma_f32_16x16x32_bf16(a1l, b1h, acc, 0, 0, 0);
            acc = __builtin_amdgcn_mfma_f32_16x16x32_bf16(a1h, b1l, acc, 0, 0, 0);

#pragma unroll
            for (int j = 0; j < 4; ++j) {
                const int r = rr0 + j;
                float v;
                if (c < SM1 && r < SM1) {
                    v = fmaxf(acc[j] * 0.125f, 0.f);
                    if (mask[((size_t)b * SM1 + r) * SM1 + c]) v -= 1e9f;
                } else {
                    v = -1e9f;
                }
                s[j] += expf(v);
            }
        }
    }
    float inv[4];
#pragma unroll
    for (int j = 0; j < 4; ++j) {
#pragma unroll
        for (int off = 8; off; off >>= 1) s[j] += __shfl_xor(s[j], off, 64);
        inv[j] = 1.0f / s[j];
    }

    // ================= pass 2: weights + PV =================
    f32x4 oacc[4];
#pragma unroll
    for (int ct = 0; ct < 4; ++ct) oacc[ct] = f32x4{0.f, 0.f, 0.f, 0.f};

    const int prow = w * 16 + lr;                // PV A-operand row (local)

    for (int kt = 0; kt < 16; ++kt) {
        const int kb0 = kt * 64;
        __syncthreads();   // previous P tile fully consumed
#pragma unroll
        for (int ct = 0; ct < 4; ++ct) {
            const int c    = kb0 + ct * 16 + lr;
            const int krow = (c < SM1) ? c : SM1 - 1;
            const size_t kbq = ((size_t)bh * SEQ + krow) * DH + ls * 8;
            const bf16x8 b0h = *(const bf16x8*)&khi[kbq];
            const bf16x8 b0l = *(const bf16x8*)&klo[kbq];
            const bf16x8 b1h = *(const bf16x8*)&khi[kbq + 32];
            const bf16x8 b1l = *(const bf16x8*)&klo[kbq + 32];

            f32x4 acc = {0.f, 0.f, 0.f, 0.f};
            acc = __builtin_amdgcn_mfma_f32_16x16x32_bf16(a0h, b0h, acc, 0, 0, 0);
            acc = __builtin_amdgcn_mfma_f32_16x16x32_bf16(a0l, b0h, acc, 0, 0, 0);
            acc = __builtin_amdgcn_mfma_f32_16x16x32_bf16(a0h, b0l, acc, 0, 0, 0);
            acc = __builtin_amdgcn_mfma_f32_16x16x32_bf16(a1h, b1h, acc, 0, 0, 0);
            acc = __builtin_amdgcn_mfma_f32_16x16x32_bf16(a1l, b1h, acc, 0, 0, 0);
            acc = __builtin_amdgcn_mfma_f32_16x16x32_bf16(a1h, b1l, acc, 0, 0, 0);

#pragma unroll
            for (int j = 0; j < 4; ++j) {
                const int r = rr0 + j;
                float v;
                if (c < SM1 && r < SM1) {
                    v = fmaxf(acc[j] * 0.125f, 0.f);
                    if (mask[((size_t)b * SM1 + r) * SM1 + c]) v -= 1e9f;
                } else {
                    v = -1e9f;
                }
                P[(w * 16 + ls * 4 + j) * 68 + ct * 16 + lr] = expf(v) * inv[j];
            }
        }
        __syncthreads();

        // ---- coalesced global weight write (256B rows) ----
        {
            const int c4 = t & 15;
#pragma unroll
            for (int it = 0; it < 4; ++it) {
                const int rl = (t >> 4) + it * 16;
                const int r  = blockIdx.x * 64 + rl;
                if (r < SM1) {
                    const int cc = kb0 + c4 * 4;
                    float4 vv = *(const float4*)&P[rl * 68 + c4 * 4];
                    float* dst = &att[((size_t)bh * SM1 + r) * SM1 + cc];
                    if (cc + 3 < SM1) {
                        *(float4*)dst = vv;
                    } else {
                        if (cc + 0 < SM1) dst[0] = vv.x;
                        if (cc + 1 < SM1) dst[1] = vv.y;
                        if (cc + 2 < SM1) dst[2] = vv.z;
                    }
                }
            }
        }

        // ---- PV MFMA ----
#pragma unroll
        for (int s2 = 0; s2 < 2; ++s2) {
            const float4 p0 = *(const float4*)&P[prow * 68 + s2 * 32 + ls * 8];
            const float4 p1 = *(const float4*)&P[prow * 68 + s2 * 32 + ls * 8 + 4];
            float pf[8] = {p0.x, p0.y, p0.z, p0.w, p1.x, p1.y, p1.z, p1.w};
            bf16x8 ph, pl;
#pragma unroll
            for (int e = 0; e < 8; ++e) {
                const __bf16 hb = (__bf16)pf[e];
                ph[e] = hb;
                pl[e] = (__bf16)(pf[e] - (float)hb);
            }
#pragma unroll
            for (int ct = 0; ct < 4; ++ct) {
                const size_t vb = ((size_t)bh * DH + ct * 16 + lr) * 1024
                                + (size_t)(kb0 + s2 * 32 + ls * 8);
                const bf16x8 vh8 = *(const bf16x8*)&vthi[vb];
                const bf16x8 vl8 = *(const bf16x8*)&vtlo[vb];
                oacc[ct] = __builtin_amdgcn_mfma_f32_16x16x32_bf16(ph, vh8, oacc[ct], 0, 0, 0);
                oacc[ct] = __builtin_amdgcn_mfma_f32_16x16x32_bf16(pl, vh8, oacc[ct], 0, 0, 0);
                oacc[ct] = __builtin_amdgcn_mfma_f32_16x16x32_bf16(ph, vl8, oacc[ct], 0, 0, 0);
            }
        }
    }

    // ---- ctx write ----
#pragma unroll
    for (int ct = 0; ct < 4; ++ct) {
#pragma unroll
        for (int j = 0; j < 4; ++j) {
            const int r = rr0 + j;
            if (r < SM1)
                ctx[((size_t)b * SM1 + r) * DMODEL + h * DH + ct * 16 + lr] = oacc[ct][j];
        }
    }
}

// ---------------------------------------------------------------
extern "C" void kernel_launch(void* const* d_in, const int* in_sizes, int n_in,
                              void* d_out, int out_size, void* d_ws, size_t ws_size,
                              hipStream_t stream) {
    const float* q    = (const float*)d_in[0];
    const float* k    = (const float*)d_in[1];
    const float* v    = (const float*)d_in[2];
    const int*   mask = (const int*)  d_in[4];
    const float* Wq   = (const float*)d_in[5];
    const float* bq   = (const float*)d_in[6];
    const float* Wk   = (const float*)d_in[7];
    const float* bk   = (const float*)d_in[8];
    const float* Wv   = (const float*)d_in[9];
    const float* bv   = (const float*)d_in[10];
    const float* Wo   = (const float*)d_in[11];
    const float* bo   = (const float*)d_in[12];

    float* out0 = (float*)d_out;                       // [2,1023,1024]
    float* att  = out0 + (size_t)2 * SM1 * DMODEL;     // [2,16,1023,1023]

    const size_t NQ  = (size_t)2 * HN * SEQ * DH;      // 2,097,152 per plane
    const size_t NVT = (size_t)2 * HN * DH * 1024;     // 2,097,152 per plane
    __bf16* ws16 = (__bf16*)d_ws;
    __bf16* qhi  = ws16;
    __bf16* qlo  = qhi + NQ;
    __bf16* khi  = qlo + NQ;
    __bf16* klo  = khi + NQ;
    __bf16* vthi = klo + NQ;
    __bf16* vtlo = vthi + NVT;
    float*  ctx  = (float*)(vtlo + NVT);               // [2,1023,1024]

    // zero V planes (padded key slot 1023 must be finite)
    hipMemsetAsync(vthi, 0, 2 * NVT * sizeof(__bf16), stream);

    gemm_mfma_kernel<0><<<dim3(16, 32), 256, 0, stream>>>(q, Wq, bq, nullptr, qhi, qlo, 2 * SEQ, SEQ);
    gemm_mfma_kernel<0><<<dim3(16, 32), 256, 0, stream>>>(k, Wk, bk, nullptr, khi, klo, 2 * SEQ, SEQ);
    gemm_mfma_kernel<2><<<dim3(16, 32), 256, 0, stream>>>(v, Wv, bv, nullptr, vthi, vtlo, 2 * SM1, SM1);

    fused_attn_kernel<<<dim3(16, HN, 2), 256, 0, stream>>>(qhi, qlo, khi, klo, vthi, vtlo, mask, att, ctx);

    gemm_mfma_kernel<1><<<dim3(16, 32), 256, 0, stream>>>(ctx, Wo, bo, out0, nullptr, nullptr, 2 * SM1, SM1);
}

// Round 6
// 316.347 us; speedup vs baseline: 1.3985x; 1.3985x over previous
//
#include <hip/hip_runtime.h>
#include <math.h>

#define HN 16
#define SEQ 1024
#define DMODEL 1024
#define DH 64
#define SM1 1023   // S-1

typedef float  f32x4  __attribute__((ext_vector_type(4)));
typedef __bf16 bf16x8 __attribute__((ext_vector_type(8)));

#define ROWB 272   // LDS row stride bytes: 16 slots of 16B + 1 pad slot

// ---------------------------------------------------------------
// MFMA GEMM with bf16 hi/lo split (3 MFMAs ~ fp32 precision).
// MODE 0: head-split bf16 hi/lo planes out[bh][s(SEQ)][64]
// MODE 1: plain fp32 out[m][1024]
// MODE 2: transposed bf16 hi/lo planes out[bh][dh][1024(pad)]
// ---------------------------------------------------------------
template<int MODE>
__global__ __launch_bounds__(256)
void gemm_mfma_kernel(const float* __restrict__ X, const float* __restrict__ W,
                      const float* __restrict__ bias, float* __restrict__ out32,
                      __bf16* __restrict__ outHi, __bf16* __restrict__ outLo,
                      int M, int rows)
{
    __shared__ __align__(16) __bf16 As[4096];
    __shared__ __align__(16) __bf16 Bs[4096];

    const int t  = threadIdx.x;
    const int w  = t >> 6, l = t & 63;
    const int lr = l & 15, ls = l >> 4;
    const int m0 = blockIdx.y * 64, n0 = blockIdx.x * 64;
    const int sr  = t >> 2;
    const int skq = t & 3;

    f32x4 acc[4];
#pragma unroll
    for (int ct = 0; ct < 4; ++ct) acc[ct] = f32x4{0.f, 0.f, 0.f, 0.f};

    const int ar   = w * 16 + lr;
    const int a_hi = ar * 128 + (((2 * ls    ) ^ (ar & 7)) << 4);
    const int a_lo = ar * 128 + (((2 * ls + 1) ^ (ar & 7)) << 4);
    const int st_hi = sr * 128 + (((2 * skq    ) ^ (sr & 7)) << 4);
    const int st_lo = sr * 128 + (((2 * skq + 1) ^ (sr & 7)) << 4);

    for (int k0 = 0; k0 < DMODEL; k0 += 32) {
        __syncthreads();
        {
            float xv[8];
            if (m0 + sr < M) {
                float4 v0 = *(const float4*)&X[(size_t)(m0 + sr) * DMODEL + k0 + skq * 8];
                float4 v1 = *(const float4*)&X[(size_t)(m0 + sr) * DMODEL + k0 + skq * 8 + 4];
                xv[0] = v0.x; xv[1] = v0.y; xv[2] = v0.z; xv[3] = v0.w;
                xv[4] = v1.x; xv[5] = v1.y; xv[6] = v1.z; xv[7] = v1.w;
            } else {
#pragma unroll
                for (int e = 0; e < 8; ++e) xv[e] = 0.f;
            }
            bf16x8 h8, l8;
#pragma unroll
            for (int e = 0; e < 8; ++e) {
                __bf16 hb = (__bf16)xv[e];
                h8[e] = hb;
                l8[e] = (__bf16)(xv[e] - (float)hb);
            }
            *(bf16x8*)((char*)As + st_hi) = h8;
            *(bf16x8*)((char*)As + st_lo) = l8;
        }
        {
            float wv[8];
#pragma unroll
            for (int e = 0; e < 8; ++e)
                wv[e] = W[(size_t)(k0 + skq * 8 + e) * DMODEL + n0 + sr];
            bf16x8 h8, l8;
#pragma unroll
            for (int e = 0; e < 8; ++e) {
                __bf16 hb = (__bf16)wv[e];
                h8[e] = hb;
                l8[e] = (__bf16)(wv[e] - (float)hb);
            }
            *(bf16x8*)((char*)Bs + st_hi) = h8;
            *(bf16x8*)((char*)Bs + st_lo) = l8;
        }
        __syncthreads();

        const bf16x8 ah = *(const bf16x8*)((const char*)As + a_hi);
        const bf16x8 al = *(const bf16x8*)((const char*)As + a_lo);
#pragma unroll
        for (int ct = 0; ct < 4; ++ct) {
            const int bc   = ct * 16 + lr;
            const int b_hi = bc * 128 + (((2 * ls    ) ^ (bc & 7)) << 4);
            const int b_lo = bc * 128 + (((2 * ls + 1) ^ (bc & 7)) << 4);
            const bf16x8 bh = *(const bf16x8*)((const char*)Bs + b_hi);
            const bf16x8 bl = *(const bf16x8*)((const char*)Bs + b_lo);
            acc[ct] = __builtin_amdgcn_mfma_f32_16x16x32_bf16(ah, bh, acc[ct], 0, 0, 0);
            acc[ct] = __builtin_amdgcn_mfma_f32_16x16x32_bf16(al, bh, acc[ct], 0, 0, 0);
            acc[ct] = __builtin_amdgcn_mfma_f32_16x16x32_bf16(ah, bl, acc[ct], 0, 0, 0);
        }
    }

#pragma unroll
    for (int ct = 0; ct < 4; ++ct) {
        const int n = n0 + ct * 16 + lr;
        const float bv = bias[n];
#pragma unroll
        for (int j = 0; j < 4; ++j) {
            const int m = m0 + w * 16 + ls * 4 + j;
            if (m >= M) continue;
            const float val = acc[ct][j] + bv;
            if (MODE == 1) {
                out32[(size_t)m * DMODEL + n] = val;
            } else {
                const int bb = m / rows, s = m - bb * rows;
                const __bf16 hb = (__bf16)val;
                const __bf16 lb = (__bf16)(val - (float)hb);
                size_t idx;
                if (MODE == 0)
                    idx = (((size_t)(bb * HN + (n >> 6)) * SEQ + s) << 6) + (n & 63);
                else
                    idx = (((size_t)(bb * HN + (n >> 6)) * DH + (n & 63)) << 10) + s;
                outHi[idx] = hb; outLo[idx] = lb;
            }
        }
    }
}

// ---------------------------------------------------------------
// QK^T -> relu/scale/mask -> exp, all LDS-fed.
// Block: 64 att-rows x 128 cols, 256 thr / 4 waves (wave = 16 rows).
// Writes exp values (unnormalized) to att region, coalesced via LDS,
// and per-(row, colblock) partial sums to partials[bh][1024][8].
// LDS rows: 17 slots of 16B (hi k-slots 0-7, lo 8-15, 1 pad).
// ---------------------------------------------------------------
__global__ __launch_bounds__(256)
void qk_exp_kernel(const __bf16* __restrict__ qhi, const __bf16* __restrict__ qlo,
                   const __bf16* __restrict__ khi, const __bf16* __restrict__ klo,
                   const int* __restrict__ mask, float* __restrict__ att,
                   float* __restrict__ partials)
{
    __shared__ __align__(16) char Qs[64 * ROWB];
    __shared__ __align__(16) char Ks[128 * ROWB];   // reused as exp tile [64][132] f32

    const int bh = blockIdx.z, b = bh >> 4;
    const int q0 = blockIdx.y * 64;
    const int c0 = blockIdx.x * 128;
    const int t = threadIdx.x, w = t >> 6, l = t & 63;
    const int lr = l & 15, ls = l >> 4;

    // ---- stage Q (64 rows x 16 chunks) ----
#pragma unroll
    for (int it = 0; it < 4; ++it) {
        const int id = t + it * 256;
        const int r = id >> 4, cw = id & 15;
        const int plane = cw >> 3, s = cw & 7;
        int qrow = q0 + r + 1; if (qrow > 1023) qrow = 1023;
        const __bf16* src = plane ? qlo : qhi;
        bf16x8 vv = *(const bf16x8*)&src[((size_t)bh * SEQ + qrow) * DH + s * 8];
        *(bf16x8*)(Qs + r * ROWB + cw * 16) = vv;
    }
    // ---- stage K (128 rows x 16 chunks) ----
#pragma unroll
    for (int it = 0; it < 8; ++it) {
        const int id = t + it * 256;
        const int r = id >> 4, cw = id & 15;
        const int plane = cw >> 3, s = cw & 7;
        int krow = c0 + r; if (krow > 1023) krow = 1023;
        const __bf16* src = plane ? klo : khi;
        bf16x8 vv = *(const bf16x8*)&src[((size_t)bh * SEQ + krow) * DH + s * 8];
        *(bf16x8*)(Ks + r * ROWB + cw * 16) = vv;
    }
    __syncthreads();

    const int ar = w * 16 + lr;
    const bf16x8 a0h = *(const bf16x8*)(Qs + ar * ROWB + ls * 16);
    const bf16x8 a1h = *(const bf16x8*)(Qs + ar * ROWB + (4 + ls) * 16);
    const bf16x8 a0l = *(const bf16x8*)(Qs + ar * ROWB + (8 + ls) * 16);
    const bf16x8 a1l = *(const bf16x8*)(Qs + ar * ROWB + (12 + ls) * 16);

    float e[8][4];
    float rsum[4] = {0.f, 0.f, 0.f, 0.f};

#pragma unroll
    for (int ct = 0; ct < 8; ++ct) {
        const int kr = ct * 16 + lr;
        const bf16x8 b0h = *(const bf16x8*)(Ks + kr * ROWB + ls * 16);
        const bf16x8 b1h = *(const bf16x8*)(Ks + kr * ROWB + (4 + ls) * 16);
        const bf16x8 b0l = *(const bf16x8*)(Ks + kr * ROWB + (8 + ls) * 16);
        const bf16x8 b1l = *(const bf16x8*)(Ks + kr * ROWB + (12 + ls) * 16);

        f32x4 acc = {0.f, 0.f, 0.f, 0.f};
        acc = __builtin_amdgcn_mfma_f32_16x16x32_bf16(a0h, b0h, acc, 0, 0, 0);
        acc = __builtin_amdgcn_mfma_f32_16x16x32_bf16(a0l, b0h, acc, 0, 0, 0);
        acc = __builtin_amdgcn_mfma_f32_16x16x32_bf16(a0h, b0l, acc, 0, 0, 0);
        acc = __builtin_amdgcn_mfma_f32_16x16x32_bf16(a1h, b1h, acc, 0, 0, 0);
        acc = __builtin_amdgcn_mfma_f32_16x16x32_bf16(a1l, b1h, acc, 0, 0, 0);
        acc = __builtin_amdgcn_mfma_f32_16x16x32_bf16(a1h, b1l, acc, 0, 0, 0);

        const int c = c0 + ct * 16 + lr;
#pragma unroll
        for (int j = 0; j < 4; ++j) {
            const int r = q0 + w * 16 + ls * 4 + j;
            float v = 0.f;
            if (r < SM1 && c < SM1) {
                float sc = fmaxf(acc[j] * 0.125f, 0.f);
                if (mask[((size_t)b * SM1 + r) * SM1 + c]) sc -= 1e9f;
                v = expf(sc);
            }
            e[ct][j] = v;
            rsum[j] += v;
        }
    }

    // partial sums over this 128-col block (reduce across lr lanes)
#pragma unroll
    for (int j = 0; j < 4; ++j) {
        rsum[j] += __shfl_xor(rsum[j], 1, 64);
        rsum[j] += __shfl_xor(rsum[j], 2, 64);
        rsum[j] += __shfl_xor(rsum[j], 4, 64);
        rsum[j] += __shfl_xor(rsum[j], 8, 64);
    }
    if (lr == 0) {
#pragma unroll
        for (int j = 0; j < 4; ++j) {
            const int r = q0 + w * 16 + ls * 4 + j;
            if (r < SM1)
                partials[(((size_t)bh << 10) + r) * 8 + blockIdx.x] = rsum[j];
        }
    }

    __syncthreads();                 // all waves done reading Ks
    float* E = (float*)Ks;           // exp tile [64][132]
#pragma unroll
    for (int ct = 0; ct < 8; ++ct)
#pragma unroll
        for (int j = 0; j < 4; ++j)
            E[(w * 16 + ls * 4 + j) * 132 + ct * 16 + lr] = e[ct][j];
    __syncthreads();

    // coalesced write of 64 rows x 128 cols
#pragma unroll
    for (int it = 0; it < 8; ++it) {
        const int id = t + it * 256;           // 2048 float4 tasks
        const int r = id >> 5, q4 = id & 31;
        const int rr = q0 + r, cc = c0 + q4 * 4;
        if (rr < SM1) {
            float4 vv = *(const float4*)&E[r * 132 + q4 * 4];
            float* dst = &att[((size_t)bh * SM1 + rr) * SM1 + cc];
            if (cc + 4 <= SM1) {
                *(float4*)dst = vv;
            } else {
                if (cc + 0 < SM1) dst[0] = vv.x;
                if (cc + 1 < SM1) dst[1] = vv.y;
                if (cc + 2 < SM1) dst[2] = vv.z;
            }
        }
    }
}

// ---------------------------------------------------------------
// PV + normalize. Block: 64 att-rows x 64 dh, 512 thr / 8 waves
// (wave = row group g = w&3, kstep parity p = w>>2).
// Reads exp from att, scales by 1/sum (from partials), writes
// normalized weights back (in place, coalesced), PV via MFMA with
// LDS-staged P (hi/lo) and V (hi/lo). Cross-parity reduce -> ctx.
// ---------------------------------------------------------------
__global__ __launch_bounds__(512)
void pv_kernel(float* att, const __bf16* __restrict__ vthi,
               const __bf16* __restrict__ vtlo, const float* __restrict__ partials,
               float* __restrict__ ctx)
{
    __shared__ __align__(16) char Ps[64 * ROWB];   // reused as red buf [64][68] f32
    __shared__ __align__(16) char Vs[64 * ROWB];
    __shared__ float invs[64];

    const int bh = blockIdx.y, b = bh >> 4, h = bh & 15;
    const int q0 = blockIdx.x * 64;
    const int t = threadIdx.x, w = t >> 6, l = t & 63;
    const int lr = l & 15, ls = l >> 4;
    const int g = w & 3, p = w >> 2;

    if (t < 64) {
        const float* pp = &partials[(((size_t)bh << 10) + q0 + t) * 8];
        float s = 0.f;
#pragma unroll
        for (int i = 0; i < 8; ++i) s += pp[i];
        invs[t] = 1.0f / s;
    }

    f32x4 oacc[4];
#pragma unroll
    for (int ct = 0; ct < 4; ++ct) oacc[ct] = f32x4{0.f, 0.f, 0.f, 0.f};

    const int pr = g * 16 + lr;

    for (int kt = 0; kt < 16; ++kt) {
        const int kb0 = kt * 64;
        __syncthreads();
        // ---- stage P: 64 rows x 8 chunks of 8 floats (1 task/thread) ----
        {
            const int r = t >> 3, ch = t & 7;
            const int rr = q0 + r;
            float pf[8];
#pragma unroll
            for (int e2 = 0; e2 < 8; ++e2) pf[e2] = 0.f;
            if (rr < SM1) {
                const int cbase = kb0 + ch * 8;
                float* gp = &att[((size_t)bh * SM1 + rr) * SM1 + cbase];
                const float iv = invs[r];
                if (cbase + 8 <= SM1) {
                    float4 v0 = *(const float4*)gp;
                    float4 v1 = *(const float4*)(gp + 4);
                    pf[0] = v0.x * iv; pf[1] = v0.y * iv; pf[2] = v0.z * iv; pf[3] = v0.w * iv;
                    pf[4] = v1.x * iv; pf[5] = v1.y * iv; pf[6] = v1.z * iv; pf[7] = v1.w * iv;
                    float4 w0 = {pf[0], pf[1], pf[2], pf[3]};
                    float4 w1 = {pf[4], pf[5], pf[6], pf[7]};
                    *(float4*)gp = w0; *(float4*)(gp + 4) = w1;
                } else {
#pragma unroll
                    for (int e2 = 0; e2 < 8; ++e2) {
                        if (cbase + e2 < SM1) {
                            pf[e2] = gp[e2] * iv;
                            gp[e2] = pf[e2];
                        }
                    }
                }
            }
            bf16x8 h8, l8;
#pragma unroll
            for (int e2 = 0; e2 < 8; ++e2) {
                const __bf16 hb = (__bf16)pf[e2];
                h8[e2] = hb;
                l8[e2] = (__bf16)(pf[e2] - (float)hb);
            }
            *(bf16x8*)(Ps + r * ROWB + ch * 16) = h8;
            *(bf16x8*)(Ps + r * ROWB + (8 + ch) * 16) = l8;
        }
        // ---- stage V: 64 dh-rows x 16 chunks (2 tasks/thread) ----
#pragma unroll
        for (int it = 0; it < 2; ++it) {
            const int id = t + it * 512;
            const int dr = id >> 4, cw = id & 15;
            const int plane = cw >> 3, s = cw & 7;
            const __bf16* src = plane ? vtlo : vthi;
            bf16x8 vv = *(const bf16x8*)&src[(((size_t)bh * DH + dr) << 10) + kb0 + s * 8];
            *(bf16x8*)(Vs + dr * ROWB + cw * 16) = vv;
        }
        __syncthreads();

        // ---- MFMA: kstep p (keys p*32..p*32+31 of tile) ----
        const bf16x8 ph = *(const bf16x8*)(Ps + pr * ROWB + (p * 4 + ls) * 16);
        const bf16x8 pl = *(const bf16x8*)(Ps + pr * ROWB + (8 + p * 4 + ls) * 16);
#pragma unroll
        for (int ct = 0; ct < 4; ++ct) {
            const int vr = ct * 16 + lr;
            const bf16x8 vh = *(const bf16x8*)(Vs + vr * ROWB + (p * 4 + ls) * 16);
            const bf16x8 vl = *(const bf16x8*)(Vs + vr * ROWB + (8 + p * 4 + ls) * 16);
            oacc[ct] = __builtin_amdgcn_mfma_f32_16x16x32_bf16(ph, vh, oacc[ct], 0, 0, 0);
            oacc[ct] = __builtin_amdgcn_mfma_f32_16x16x32_bf16(pl, vh, oacc[ct], 0, 0, 0);
            oacc[ct] = __builtin_amdgcn_mfma_f32_16x16x32_bf16(ph, vl, oacc[ct], 0, 0, 0);
        }
    }

    // ---- cross-parity reduce and ctx write ----
    __syncthreads();
    float* red = (float*)Ps;   // [64][68]
    if (p == 1) {
#pragma unroll
        for (int ct = 0; ct < 4; ++ct)
#pragma unroll
            for (int j = 0; j < 4; ++j)
                red[(g * 16 + ls * 4 + j) * 68 + ct * 16 + lr] = oacc[ct][j];
    }
    __syncthreads();
    if (p == 0) {
#pragma unroll
        for (int ct = 0; ct < 4; ++ct)
#pragma unroll
            for (int j = 0; j < 4; ++j) {
                const int r = q0 + g * 16 + ls * 4 + j;
                if (r < SM1)
                    ctx[((size_t)b * SM1 + r) * DMODEL + h * DH + ct * 16 + lr] =
                        oacc[ct][j] + red[(g * 16 + ls * 4 + j) * 68 + ct * 16 + lr];
            }
    }
}

// ---------------------------------------------------------------
extern "C" void kernel_launch(void* const* d_in, const int* in_sizes, int n_in,
                              void* d_out, int out_size, void* d_ws, size_t ws_size,
                              hipStream_t stream) {
    const float* q    = (const float*)d_in[0];
    const float* k    = (const float*)d_in[1];
    const float* v    = (const float*)d_in[2];
    const int*   mask = (const int*)  d_in[4];
    const float* Wq   = (const float*)d_in[5];
    const float* bq   = (const float*)d_in[6];
    const float* Wk   = (const float*)d_in[7];
    const float* bk   = (const float*)d_in[8];
    const float* Wv   = (const float*)d_in[9];
    const float* bv   = (const float*)d_in[10];
    const float* Wo   = (const float*)d_in[11];
    const float* bo   = (const float*)d_in[12];

    float* out0 = (float*)d_out;                       // [2,1023,1024]
    float* att  = out0 + (size_t)2 * SM1 * DMODEL;     // [2,16,1023,1023]

    const size_t NQ  = (size_t)2 * HN * SEQ * DH;      // 2,097,152 per plane
    const size_t NVT = (size_t)2 * HN * DH * 1024;     // 2,097,152 per plane
    __bf16* ws16 = (__bf16*)d_ws;
    __bf16* qhi  = ws16;
    __bf16* qlo  = qhi + NQ;
    __bf16* khi  = qlo + NQ;
    __bf16* klo  = khi + NQ;
    __bf16* vthi = klo + NQ;
    __bf16* vtlo = vthi + NVT;
    float*  ctx  = (float*)(vtlo + NVT);               // [2,1023,1024]
    float*  partials = ctx + (size_t)2 * SM1 * DMODEL; // [32,1024,8]

    hipMemsetAsync(vthi, 0, 2 * NVT * sizeof(__bf16), stream);

    gemm_mfma_kernel<0><<<dim3(16, 32), 256, 0, stream>>>(q, Wq, bq, nullptr, qhi, qlo, 2 * SEQ, SEQ);
    gemm_mfma_kernel<0><<<dim3(16, 32), 256, 0, stream>>>(k, Wk, bk, nullptr, khi, klo, 2 * SEQ, SEQ);
    gemm_mfma_kernel<2><<<dim3(16, 32), 256, 0, stream>>>(v, Wv, bv, nullptr, vthi, vtlo, 2 * SM1, SM1);

    qk_exp_kernel<<<dim3(8, 16, 32), 256, 0, stream>>>(qhi, qlo, khi, klo, mask, att, partials);
    pv_kernel<<<dim3(16, 32), 512, 0, stream>>>(att, vthi, vtlo, partials, ctx);

    gemm_mfma_kernel<1><<<dim3(16, 32), 256, 0, stream>>>(ctx, Wo, bo, out0, nullptr, nullptr, 2 * SM1, SM1);
}